// Round 11
// baseline (118.519 us; speedup 1.0000x reference)
//
#include <hip/hip_runtime.h>

// KANConv2d, round 11: R6/R10 dataflow + 3-phase substeps (T3 fine interleave).
// out[b,o,h,w] = sum_{c,tap,j} Wc[o,c,tap,j] * f_j(xp[b,c,h+dh,w+dw])
// f = {silu(v), B_0..B_6(v)} cardinal cubic B-splines (t = 2v+5), 8 bf16/granule.
// Structure: grid 256 (b x hquad), 1 block/CU, 8 waves (wave = 64o x 64w x 1h, 2x2 frags).
//   A: global_load_lds DMA, triple-buffered At[dh], issued 2 substeps ahead, one
//      chunk per phase; counted vmcnt only at substep-boundary phases (R10 counts).
//   B: features computed in-kernel, double-buffered per cb; FEATW split across
//      dh==2's three phases; published via lgkmcnt(0) at the dh2 boundary.
//   Each phase: {1 DMA chunk + 8 ds_read} -> barrier -> {setprio 8xMFMA} (T3+T5).

#define BB 16
#define CC 64
#define HH 64
#define WW 64
#define OO 128

typedef __bf16 bf16x8 __attribute__((ext_vector_type(8)));
typedef float f32x16 __attribute__((ext_vector_type(16)));

__device__ __forceinline__ bf16x8 as_bf16x8(uint4 v) { return __builtin_bit_cast(bf16x8, v); }
__device__ __forceinline__ unsigned bfb(float f) {
    return (unsigned)__builtin_bit_cast(unsigned short, (__bf16)f);
}

// 8-feature granule {silu(v), B_0(v)..B_6(v)} packed as 8 bf16 via 128-bit shift scatter.
__device__ __forceinline__ uint4 feat_granule(float v) {
    const float silu = __fdividef(v, 1.f + __expf(-v));
    const float t  = fmaf(2.f, v, 5.f);
    const float fi = floorf(t);
    const float u  = t - fi;
    const float um = 1.f - u;
    const float u2 = u * u, u3 = u2 * u;
    const float k0 = um * um * um * (1.f / 6.f);
    const float k1 = fmaf(0.5f, u3, (2.f / 3.f) - u2);
    const float k2 = fmaf(-0.5f, u3, fmaf(0.5f, u2, fmaf(0.5f, u, 1.f / 6.f)));
    const float k3 = u3 * (1.f / 6.f);
    const bool valid = (t >= 0.f) && (t < 10.f);
    unsigned long long K =
        (unsigned long long)bfb(k0)         |
        ((unsigned long long)bfb(k1) << 16) |
        ((unsigned long long)bfb(k2) << 32) |
        ((unsigned long long)bfb(k3) << 48);
    if (!valid) K = 0ull;
    const int ic = min(max((int)fi, -2), 9);
    const int sh = 16 * ic - 32;            // [-64, 112]
    unsigned __int128 P = (sh >= 0) ? ((unsigned __int128)K << sh)
                                    : ((unsigned __int128)K >> (-sh));
    uint4 pk = __builtin_bit_cast(uint4, P);
    pk.x = (pk.x & 0xFFFF0000u) | bfb(silu);
    return pk;
}

// ---------------- weight prep: Wb[cb][tap][c_l][o][j] bf16, j contiguous ----------------
__global__ __launch_bounds__(256) void kan_wprep(
    const float* __restrict__ beta, const float* __restrict__ spl,
    const float* __restrict__ cf, uint4* __restrict__ wb)
{
    int t = blockIdx.x * 256 + threadIdx.x;      // 73728 = (o, c, tap)
    int tap = t % 9;
    int c   = (t / 9) & 63;
    int o   = t / 576;
    int base = (o * CC + c) * 9 + tap;
    float bv = beta[base];
    float sv = spl[base];
    float f[8];
    f[0] = bv;
    #pragma unroll
    for (int s = 0; s < 7; ++s)
        f[1 + s] = sv * cf[((s * OO + o) * CC + c) * 9 + tap];
    uint4 pk;
    pk.x = bfb(f[0]) | (bfb(f[1]) << 16);
    pk.y = bfb(f[2]) | (bfb(f[3]) << 16);
    pk.z = bfb(f[4]) | (bfb(f[5]) << 16);
    pk.w = bfb(f[6]) | (bfb(f[7]) << 16);
    int cb = c >> 2, cl = c & 3;
    wb[((cb * 9 + tap) * 4 + cl) * OO + o] = pk;
}

// ---------------- main implicit GEMM ----------------
__global__ __launch_bounds__(512, 2) void kan_mfma8(
    const float* __restrict__ x, const uint4* __restrict__ wb,
    float* __restrict__ out)
{
    // B/features: [buf][(cl*6 + row)*66 + col], 1584 granules/buf
    __shared__ uint4 Bt[2][1584];
    // A/weights substep tile: TRIPLE buffered, At[dh] holds (cb, dh)
    __shared__ uint4 At[3][1536];

    const int tid  = threadIdx.x;
    const int blk  = blockIdx.x;
    const int hq   = blk & 15;
    const int b    = blk >> 4;
    const int h0   = hq << 2;          // output rows h0..h0+3; input rows h0-1..h0+4

    const int ww    = tid >> 6;        // wave 0..7
    const int lane  = tid & 63;
    const int lo    = lane & 31;
    const int hi    = lane >> 5;
    const int ohalf = ww & 1;
    const int hrow  = ww >> 1;         // 0..3

    f32x16 acc[2][2] = {};             // [oi][wi]
    float xv[4];

    // ---- hoisted x addressing: per-thread clamped pointer + validity mask ----
    const float* xptr[4];
    float xmsk[4];
    #pragma unroll
    for (int k = 0; k < 4; ++k) {
        const int g   = tid + k * 512;
        const int gg  = (g < 1584) ? g : 0;
        const int cl_ = gg / 396;
        const int r_  = (gg % 396) / 66;
        const int co_ = gg % 66;
        const int hx  = h0 - 1 + r_;
        const int wx  = co_ - 1;
        const bool ok = (g < 1584) && ((unsigned)hx < 64u) && ((unsigned)wx < 64u);
        const int hc  = min(max(hx, 0), 63);
        const int wc  = min(max(wx, 0), 63);
        xptr[k] = x + ((b * CC + cl_) * HH + hc) * WW + wc;
        xmsk[k] = ok ? 1.f : 0.f;
    }

    // raw loads (mask applied at consumption in FEATW)
    #define XLOAD(cbi) do {                                                   \
        _Pragma("unroll")                                                     \
        for (int k = 0; k < 4; ++k) xv[k] = xptr[k][(cbi) * 4 * HH * WW];     \
    } while (0)

    // feature compute + LDS write, granule range [k0,k1)
    #define FEATW_K(bufi, k0, k1) do {                                        \
        _Pragma("unroll")                                                     \
        for (int k = k0; k < k1; ++k) {                                       \
            const int g = tid + k * 512;                                      \
            if (g < 1584) Bt[bufi][g] = feat_granule(xmsk[k] * xv[k]);        \
        }                                                                     \
    } while (0)

    // one A-DMA chunk (1KB x 8 waves) of substep slice (cb1, dh1) into At[bufi]
    #define ADMA1(bufi, cb1, dh1, i) do {                                     \
        const uint4* asrc = wb + ((cb1) * 4608 + (dh1) * 1536)                \
                            + ww * 192 + (i) * 64 + lane;                     \
        __builtin_amdgcn_global_load_lds(                                     \
            (const __attribute__((address_space(1))) void*)asrc,              \
            (__attribute__((address_space(3))) void*)                         \
                &At[bufi][ww * 192 + (i) * 64],                               \
            16, 0, 0);                                                        \
    } while (0)

    // prologue: Bt[0] <- features(cb0); At[0] <- (0,0); At[1] <- (0,1); full drain once
    XLOAD(0);
    #pragma unroll
    for (int i = 0; i < 3; ++i) ADMA1(0, 0, 0, i);
    #pragma unroll
    for (int i = 0; i < 3; ++i) ADMA1(1, 0, 1, i);
    FEATW_K(0, 0, 4);
    asm volatile("s_waitcnt vmcnt(0) lgkmcnt(0)" ::: "memory");
    __builtin_amdgcn_s_barrier();
    __builtin_amdgcn_sched_barrier(0);

    #pragma unroll 1
    for (int cb = 0; cb < 16; ++cb) {
        const uint4* Bb = Bt[cb & 1];

        #pragma unroll
        for (int dh = 0; dh < 3; ++dh) {
            // substep s = cb*3+dh reads At[dh] (landed 2 substeps ago) and Bt[cb&1]
            if (dh == 0 && cb < 15) XLOAD(cb + 1);

            const uint4* Ab = At[dh];

            #pragma unroll
            for (int tl = 0; tl < 3; ++tl) {     // phase = (s, tl); tap = dh*3+tl
                // ---- stage: one DMA chunk for substep s+2 into At[(dh+2)%3] ----
                if (dh == 0)                      ADMA1(2, cb, 2, tl);
                else if (dh == 1) { if (cb < 15)  ADMA1(0, cb + 1, 0, tl); }
                else              { if (cb < 15)  ADMA1(1, cb + 1, 1, tl); }

                // ---- ds_read this phase's 8 fragments ----
                bf16x8 Af[2][2], Bf[2][2];       // [kh][oi] / [kh][wi]
                #pragma unroll
                for (int kh = 0; kh < 2; ++kh) {
                    const int arow = (tl * 4 + kh * 2 + hi) * 128 + ohalf * 64 + lo;
                    Af[kh][0] = as_bf16x8(Ab[arow]);
                    Af[kh][1] = as_bf16x8(Ab[arow + 32]);
                    const int brow = ((kh * 2 + hi) * 6 + hrow + dh) * 66 + tl + lo;
                    Bf[kh][0] = as_bf16x8(Bb[brow]);
                    Bf[kh][1] = as_bf16x8(Bb[brow + 32]);
                }

                // ---- FEATW spread over dh==2's phases (writes Bt[(cb+1)&1]) ----
                if (dh == 2 && cb < 15) {
                    if (tl == 0)      FEATW_K((cb + 1) & 1, 0, 2);
                    else if (tl == 1) FEATW_K((cb + 1) & 1, 2, 3);
                    else              FEATW_K((cb + 1) & 1, 3, 4);
                }

                // ---- substep-boundary waits at tl==2 only (R10 counts) ----
                if (tl == 2 && !(cb == 15 && dh == 2)) {
                    if (dh == 2) {
                        asm volatile("s_waitcnt vmcnt(3) lgkmcnt(0)" ::: "memory");
                    } else if (dh == 0) {
                        if (cb < 15) asm volatile("s_waitcnt vmcnt(7)" ::: "memory");
                        else         asm volatile("s_waitcnt vmcnt(3)" ::: "memory");
                    } else {
                        if (cb < 15) asm volatile("s_waitcnt vmcnt(3)" ::: "memory");
                        else         asm volatile("s_waitcnt vmcnt(0)" ::: "memory");
                    }
                }

                // ---- phase barrier (bare aligner except at boundaries) ----
                __builtin_amdgcn_sched_barrier(0);
                if (!(cb == 15 && dh == 2 && tl == 2)) __builtin_amdgcn_s_barrier();
                __builtin_amdgcn_sched_barrier(0);

                // ---- isolated MFMA cluster (T5 pays in phase-split regime) ----
                __builtin_amdgcn_s_setprio(1);
                #pragma unroll
                for (int oi = 0; oi < 2; ++oi)
                    #pragma unroll
                    for (int wi = 0; wi < 2; ++wi)
                        #pragma unroll
                        for (int kh = 0; kh < 2; ++kh)
                            acc[oi][wi] = __builtin_amdgcn_mfma_f32_32x32x16_bf16(
                                Af[kh][oi], Bf[kh][wi], acc[oi][wi], 0, 0, 0);
                __builtin_amdgcn_s_setprio(0);
            }
        }
    }

    // ---- store: w-coalesced dword stores ----
    const int h = h0 + hrow;
    #pragma unroll
    for (int oi = 0; oi < 2; ++oi)
        #pragma unroll
        for (int wi = 0; wi < 2; ++wi) {
            const int wc = wi * 32 + lo;
            #pragma unroll
            for (int r = 0; r < 16; ++r) {
                const int o = ohalf * 64 + oi * 32 + (r & 3) + ((r >> 2) << 3) + (hi << 2);
                out[((b * OO + o) * HH + h) * WW + wc] = acc[oi][wi][r];
            }
        }
}

extern "C" void kernel_launch(void* const* d_in, const int* in_sizes, int n_in,
                              void* d_out, int out_size, void* d_ws, size_t ws_size,
                              hipStream_t stream) {
    const float* x    = (const float*)d_in[0];
    const float* beta = (const float*)d_in[1];
    const float* spl  = (const float*)d_in[2];
    const float* cf   = (const float*)d_in[3];
    float* out = (float*)d_out;
    uint4* wb  = (uint4*)d_ws;          // 73728 granules = 1.18 MB

    kan_wprep<<<288, 256, 0, stream>>>(beta, spl, cf, wb);
    kan_mfma8<<<BB * 16, 512, 0, stream>>>(x, wb, out);
}

// Round 12
// 82.720 us; speedup vs baseline: 1.4328x; 1.4328x over previous
//
#include <hip/hip_runtime.h>

// KANConv2d, round 12: R10 + cross-barrier fragment pre-reads (kill substep refill).
// out[b,o,h,w] = sum_{c,tap,j} Wc[o,c,tap,j] * f_j(xp[b,c,h+dh,w+dw])
// f = {silu(v), B_0..B_6(v)} cardinal cubic B-splines (t = 2v+5), 8 bf16/granule.
// Structure: grid 256 (b x hquad), 1 block/CU, 8 waves (wave = 64o x 64w x 1h, 2x2 frags).
//   A: global_load_lds DMA, triple-buffered At[dh], issued 2 substeps ahead.
//   NEW: tl0 fragments for substep s+1 are ds_read at the END of substep s into
//   persistent regs pA/pB (slot already landed), so the first MFMA after each
//   barrier issues immediately — no post-barrier port refill stall. Waits
//   tightened (vmcnt 4/0/0) so the pre-read slot is always resident.

#define BB 16
#define CC 64
#define HH 64
#define WW 64
#define OO 128

typedef __bf16 bf16x8 __attribute__((ext_vector_type(8)));
typedef float f32x16 __attribute__((ext_vector_type(16)));

__device__ __forceinline__ bf16x8 as_bf16x8(uint4 v) { return __builtin_bit_cast(bf16x8, v); }
__device__ __forceinline__ unsigned bfb(float f) {
    return (unsigned)__builtin_bit_cast(unsigned short, (__bf16)f);
}

// 8-feature granule {silu(v), B_0(v)..B_6(v)} packed as 8 bf16 via 128-bit shift scatter.
__device__ __forceinline__ uint4 feat_granule(float v) {
    const float silu = __fdividef(v, 1.f + __expf(-v));
    const float t  = fmaf(2.f, v, 5.f);
    const float fi = floorf(t);
    const float u  = t - fi;
    const float um = 1.f - u;
    const float u2 = u * u, u3 = u2 * u;
    const float k0 = um * um * um * (1.f / 6.f);
    const float k1 = fmaf(0.5f, u3, (2.f / 3.f) - u2);
    const float k2 = fmaf(-0.5f, u3, fmaf(0.5f, u2, fmaf(0.5f, u, 1.f / 6.f)));
    const float k3 = u3 * (1.f / 6.f);
    const bool valid = (t >= 0.f) && (t < 10.f);
    unsigned long long K =
        (unsigned long long)bfb(k0)         |
        ((unsigned long long)bfb(k1) << 16) |
        ((unsigned long long)bfb(k2) << 32) |
        ((unsigned long long)bfb(k3) << 48);
    if (!valid) K = 0ull;
    const int ic = min(max((int)fi, -2), 9);
    const int sh = 16 * ic - 32;            // [-64, 112]
    unsigned __int128 P = (sh >= 0) ? ((unsigned __int128)K << sh)
                                    : ((unsigned __int128)K >> (-sh));
    uint4 pk = __builtin_bit_cast(uint4, P);
    pk.x = (pk.x & 0xFFFF0000u) | bfb(silu);
    return pk;
}

// ---------------- weight prep: Wb[cb][tap][c_l][o][j] bf16, j contiguous ----------------
__global__ __launch_bounds__(256) void kan_wprep(
    const float* __restrict__ beta, const float* __restrict__ spl,
    const float* __restrict__ cf, uint4* __restrict__ wb)
{
    int t = blockIdx.x * 256 + threadIdx.x;      // 73728 = (o, c, tap)
    int tap = t % 9;
    int c   = (t / 9) & 63;
    int o   = t / 576;
    int base = (o * CC + c) * 9 + tap;
    float bv = beta[base];
    float sv = spl[base];
    float f[8];
    f[0] = bv;
    #pragma unroll
    for (int s = 0; s < 7; ++s)
        f[1 + s] = sv * cf[((s * OO + o) * CC + c) * 9 + tap];
    uint4 pk;
    pk.x = bfb(f[0]) | (bfb(f[1]) << 16);
    pk.y = bfb(f[2]) | (bfb(f[3]) << 16);
    pk.z = bfb(f[4]) | (bfb(f[5]) << 16);
    pk.w = bfb(f[6]) | (bfb(f[7]) << 16);
    int cb = c >> 2, cl = c & 3;
    wb[((cb * 9 + tap) * 4 + cl) * OO + o] = pk;
}

// ---------------- main implicit GEMM ----------------
__global__ __launch_bounds__(512, 2) void kan_mfma9(
    const float* __restrict__ x, const uint4* __restrict__ wb,
    float* __restrict__ out)
{
    // B/features: [buf][(cl*6 + row)*66 + col], 1584 granules/buf
    __shared__ uint4 Bt[2][1584];
    // A/weights substep tile: TRIPLE buffered, At[dh] holds (cb, dh)
    __shared__ uint4 At[3][1536];

    const int tid  = threadIdx.x;
    const int blk  = blockIdx.x;
    const int hq   = blk & 15;
    const int b    = blk >> 4;
    const int h0   = hq << 2;          // output rows h0..h0+3; input rows h0-1..h0+4

    const int ww    = tid >> 6;        // wave 0..7
    const int lane  = tid & 63;
    const int lo    = lane & 31;
    const int hi    = lane >> 5;
    const int ohalf = ww & 1;
    const int hrow  = ww >> 1;         // 0..3

    f32x16 acc[2][2] = {};             // [oi][wi]
    float xv[4];
    uint4 pA[2][2], pB[2][2];          // persistent tl0 fragments (cross-barrier)

    // ---- x loads for channel-block cbi: 1584 granule-pixels (4cl x 6rows x 66) ----
    #define XLOAD(cbi) do {                                                   \
        _Pragma("unroll")                                                     \
        for (int k = 0; k < 4; ++k) {                                         \
            const int g = tid + k * 512;                                      \
            float v = 0.f;                                                    \
            if (g < 1584) {                                                   \
                const int cl_ = g / 396;                                      \
                const int r_  = (g % 396) / 66;                               \
                const int co_ = g % 66;                                       \
                const int hx  = h0 - 1 + r_;                                  \
                const int wx  = co_ - 1;                                      \
                if ((unsigned)hx < 64u && (unsigned)wx < 64u)                 \
                    v = x[((b * CC + (cbi) * 4 + cl_) * HH + hx) * WW + wx];  \
            }                                                                 \
            xv[k] = v;                                                        \
        }                                                                     \
    } while (0)

    // ---- feature compute + LDS write into Bt[bufi] ----
    #define FEATW(bufi) do {                                                  \
        _Pragma("unroll")                                                     \
        for (int k = 0; k < 4; ++k) {                                         \
            const int g = tid + k * 512;                                      \
            if (g < 1584) Bt[bufi][g] = feat_granule(xv[k]);                  \
        }                                                                     \
    } while (0)

    // ---- DMA one A substep slice (cb1, dh1) into At[bufi]: 24 x 1KB, 3/wave ----
    #define ADMA(bufi, cb1, dh1) do {                                         \
        const uint4* asrc = wb + ((cb1) * 4608 + (dh1) * 1536)                \
                            + ww * 192 + lane;                                \
        _Pragma("unroll")                                                     \
        for (int i = 0; i < 3; ++i)                                           \
            __builtin_amdgcn_global_load_lds(                                 \
                (const __attribute__((address_space(1))) void*)(asrc + i*64), \
                (__attribute__((address_space(3))) void*)                     \
                    &At[bufi][ww * 192 + i * 64],                             \
                16, 0, 0);                                                    \
    } while (0)

    #define READ_A(dst, Ab, tl) do {                                          \
        _Pragma("unroll")                                                     \
        for (int kh = 0; kh < 2; ++kh) {                                      \
            const int arow = ((tl) * 4 + kh * 2 + hi) * 128 + ohalf * 64 + lo;\
            dst[kh][0] = (Ab)[arow];                                          \
            dst[kh][1] = (Ab)[arow + 32];                                     \
        }                                                                     \
    } while (0)

    #define READ_B(dst, Bb, dhv, tl) do {                                     \
        _Pragma("unroll")                                                     \
        for (int kh = 0; kh < 2; ++kh) {                                      \
            const int brow = ((kh * 2 + hi) * 6 + hrow + (dhv)) * 66          \
                             + (tl) + lo;                                     \
            dst[kh][0] = (Bb)[brow];                                          \
            dst[kh][1] = (Bb)[brow + 32];                                     \
        }                                                                     \
    } while (0)

    #define MFMA8(A_, B_) do {                                                \
        __builtin_amdgcn_s_setprio(1);                                        \
        _Pragma("unroll")                                                     \
        for (int oi = 0; oi < 2; ++oi)                                        \
            _Pragma("unroll")                                                 \
            for (int wi = 0; wi < 2; ++wi)                                    \
                _Pragma("unroll")                                             \
                for (int kh = 0; kh < 2; ++kh)                                \
                    acc[oi][wi] = __builtin_amdgcn_mfma_f32_32x32x16_bf16(    \
                        as_bf16x8(A_[kh][oi]), as_bf16x8(B_[kh][wi]),         \
                        acc[oi][wi], 0, 0, 0);                                \
        __builtin_amdgcn_s_setprio(0);                                        \
    } while (0)

    // prologue: Bt[0] <- features(cb0); At[0] <- (0,0); At[1] <- (0,1); full drain once
    XLOAD(0);
    ADMA(0, 0, 0);
    ADMA(1, 0, 1);
    FEATW(0);
    asm volatile("s_waitcnt vmcnt(0) lgkmcnt(0)" ::: "memory");
    __builtin_amdgcn_s_barrier();
    __builtin_amdgcn_sched_barrier(0);
    READ_A(pA, At[0], 0);              // tl0 A for substep 0 (B refilled in dh0 path)

    #pragma unroll 1
    for (int cb = 0; cb < 16; ++cb) {
        const uint4* Bb = Bt[cb & 1];

        #pragma unroll
        for (int dh = 0; dh < 3; ++dh) {
            // substep s = cb*3+dh reads At[dh] + pre-read slot At[(dh+1)%3]
            if (dh == 0) {
                READ_B(pB, Bb, 0, 0);          // tl0 B (couldn't pre-read across cb)
                ADMA(2, cb, 2);
                __builtin_amdgcn_sched_barrier(0);   // pin ADMA before XLOAD in queue
                if (cb < 15) XLOAD(cb + 1);
            } else if (dh == 1) {
                if (cb < 15) ADMA(0, cb + 1, 0);
            } else {
                if (cb < 15) ADMA(1, cb + 1, 1);
            }

            const uint4* Ab = At[dh];

            // ---- tl0: fragments already in registers ----
            MFMA8(pA, pB);

            // ---- tl1 ----
            uint4 a1[2][2], b1[2][2];
            READ_A(a1, Ab, 1);
            READ_B(b1, Bb, dh, 1);
            MFMA8(a1, b1);

            // ---- tl2 + pre-reads for next substep's tl0 ----
            uint4 a2[2][2], b2[2][2];
            READ_A(a2, Ab, 2);
            READ_B(b2, Bb, dh, 2);
            if (!(cb == 15 && dh == 2)) {
                READ_A(pA, At[(dh + 1) % 3], 0);   // next slot landed (tight vmcnt)
            }
            if (dh < 2) READ_B(pB, Bb, dh + 1, 0); // same Bt buffer within cb
            MFMA8(a2, b2);

            if (dh == 2 && cb < 15) FEATW((cb + 1) & 1);  // publish next-cb features

            // ---- raw barrier with tightened counted waits ----
            // Invariant: the slot pre-read during the NEXT substep (DMA'd this
            // substep or earlier) must be resident when we cross this barrier.
            if (!(cb == 15 && dh == 2)) {
                if (dh == 0) {
                    if (cb < 15) asm volatile("s_waitcnt vmcnt(4)" ::: "memory");
                    else         asm volatile("s_waitcnt vmcnt(0)" ::: "memory");
                } else if (dh == 1) {
                    asm volatile("s_waitcnt vmcnt(0)" ::: "memory");
                } else {
                    asm volatile("s_waitcnt vmcnt(0) lgkmcnt(0)" ::: "memory");
                }
                __builtin_amdgcn_s_barrier();
                __builtin_amdgcn_sched_barrier(0);
            }
        }
    }

    // ---- store: w-coalesced dword stores ----
    const int h = h0 + hrow;
    #pragma unroll
    for (int oi = 0; oi < 2; ++oi)
        #pragma unroll
        for (int wi = 0; wi < 2; ++wi) {
            const int wc = wi * 32 + lo;
            #pragma unroll
            for (int r = 0; r < 16; ++r) {
                const int o = ohalf * 64 + oi * 32 + (r & 3) + ((r >> 2) << 3) + (hi << 2);
                out[((b * OO + o) * HH + h) * WW + wc] = acc[oi][wi][r];
            }
        }
}

extern "C" void kernel_launch(void* const* d_in, const int* in_sizes, int n_in,
                              void* d_out, int out_size, void* d_ws, size_t ws_size,
                              hipStream_t stream) {
    const float* x    = (const float*)d_in[0];
    const float* beta = (const float*)d_in[1];
    const float* spl  = (const float*)d_in[2];
    const float* cf   = (const float*)d_in[3];
    float* out = (float*)d_out;
    uint4* wb  = (uint4*)d_ws;          // 73728 granules = 1.18 MB

    kan_wprep<<<288, 256, 0, stream>>>(beta, spl, cf, wb);
    kan_mfma9<<<BB * 16, 512, 0, stream>>>(x, wb, out);
}